// Round 1
// 784.395 us; speedup vs baseline: 1.1038x; 1.1038x over previous
//
#include <hip/hip_runtime.h>
#include <stdint.h>

#define BM 128
#define BN 128
#define BK 32
#define DIMD 512
#define NROWS 65536
#define QOFF 1
#define PERPOFF 33554433
#define PROBSOFF 33554434
#define NELEM 33554432

typedef __attribute__((ext_vector_type(8))) short bf16x8;
typedef __attribute__((ext_vector_type(4))) short s16x4;
typedef __attribute__((ext_vector_type(4))) float f32x4;

typedef const __attribute__((address_space(1))) void* gas_ptr;
typedef __attribute__((address_space(3))) void* las_ptr;

__device__ __forceinline__ short f2bf(float x){
  uint32_t u = __builtin_bit_cast(uint32_t, x);
  uint32_t r = (u + 0x7fffu + ((u >> 16) & 1u)) >> 16;
  return (short)(uint16_t)r;
}
__device__ __forceinline__ float bf2f(short h){
  return __builtin_bit_cast(float, ((uint32_t)(uint16_t)h) << 16);
}

// ---------------- helpers for k_gemm_mean (unchanged layout, no swizzle) ----------------
__device__ __forceinline__ void stage_bf16(const short* __restrict__ g, int row0, int ld, int k0,
                                           short* lds){
  int tid = threadIdx.x;
#pragma unroll
  for (int i = 0; i < 2; ++i){
    int t = tid + i * 256;
    int row = t >> 2, c = t & 3;
    const short* src = g + (long)(row0 + row) * ld + k0 + c * 8;
    __builtin_amdgcn_global_load_lds((gas_ptr)src, (las_ptr)(lds + t * 8), 16, 0, 0);
  }
}

__device__ __forceinline__ void stage_f32_split(const float* __restrict__ g, int row0, int ld, int k0,
                                                short* hi, short* lo){
  int tid = threadIdx.x;
#pragma unroll
  for (int i = 0; i < 4; ++i){
    int t = tid + i * 256;
    int row = t >> 3, c = t & 7;
    const float4 v = *(const float4*)(g + (long)(row0 + row) * ld + k0 + c * 4);
    short h0 = f2bf(v.x), h1 = f2bf(v.y), h2 = f2bf(v.z), h3 = f2bf(v.w);
    s16x4 hv; hv[0] = h0; hv[1] = h1; hv[2] = h2; hv[3] = h3;
    s16x4 lv;
    lv[0] = f2bf(v.x - bf2f(h0)); lv[1] = f2bf(v.y - bf2f(h1));
    lv[2] = f2bf(v.z - bf2f(h2)); lv[3] = f2bf(v.w - bf2f(h3));
    *(s16x4*)(hi + row * BK + c * 4) = hv;
    *(s16x4*)(lo + row * BK + c * 4) = lv;
  }
}

__device__ __forceinline__ bf16x8 frag(const short* lds, int r, int q){
  return *(const bf16x8*)(lds + r * BK + q * 8);
}

// ---------------- swizzled helpers for k_fused ----------------
// chunk swizzle: 2-way (free) LDS bank aliasing instead of 8-way on frag reads.
__device__ __forceinline__ int swz4(int row, int c){ return c ^ ((row >> 1) & 3); }

__device__ __forceinline__ bf16x8 frag_s(const short* lds, int r, int q){
  return *(const bf16x8*)(lds + r * BK + swz4(r, q) * 8);
}

// stage [512 rows][32 k] bf16 tile; LDS linear, SOURCE chunk pre-swizzled (rule: both-sides-or-neither)
__device__ __forceinline__ void stage_B512(const short* __restrict__ g, int k0, short* lds){
  int tid = threadIdx.x;
#pragma unroll
  for (int i = 0; i < 4; ++i){
    int t = tid + i * 512;
    int row = t >> 2, c = t & 3;
    int cs = swz4(row, c);
    __builtin_amdgcn_global_load_lds((gas_ptr)(g + (long)row * DIMD + k0 + cs * 8),
                                     (las_ptr)(lds + t * 8), 16, 0, 0);
  }
}

// stage [64 rows][32 k] hi+lo: waves 0-3 stage hi, waves 4-7 stage lo
__device__ __forceinline__ void stage_A64(const short* __restrict__ gh, const short* __restrict__ gl,
                                          int n0, int k0, short* Ah, short* Al){
  int tid = threadIdx.x;
  int t = tid & 255;
  int row = t >> 2, c = t & 3;
  int cs = swz4(row, c);
  const short* g = (tid < 256) ? gh : gl;
  short* lds = (tid < 256) ? Ah : Al;
  __builtin_amdgcn_global_load_lds((gas_ptr)(g + (long)(n0 + row) * DIMD + k0 + cs * 8),
                                   (las_ptr)(lds + t * 8), 16, 0, 0);
}

__device__ __forceinline__ void stage_A64h(const short* __restrict__ g, int n0, int k0, short* Ah){
  int tid = threadIdx.x;
  if (tid < 256){
    int row = tid >> 2, c = tid & 3;
    int cs = swz4(row, c);
    __builtin_amdgcn_global_load_lds((gas_ptr)(g + (long)(n0 + row) * DIMD + k0 + cs * 8),
                                     (las_ptr)(Ah + tid * 8), 16, 0, 0);
  }
}

// ---------------- weight conversion ----------------
__global__ __launch_bounds__(256) void k_convert_w(
    const float* __restrict__ meanW, const float* __restrict__ lvW, const float* __restrict__ emb,
    short* __restrict__ MWThi, short* __restrict__ MWTlo,
    short* __restrict__ VWThi, short* __restrict__ VWTlo,
    short* __restrict__ E, short* __restrict__ ET, float* __restrict__ enorm)
{
  int b = blockIdx.x;
  int tid = threadIdx.x;
  float esum = 0.f;
  for (int j = tid; j < 512; j += 256){
    float w = meanW[b * 512 + j];
    short h = f2bf(w); short l = f2bf(w - bf2f(h));
    MWThi[j * 512 + b] = h; MWTlo[j * 512 + b] = l;
    float v = lvW[b * 512 + j];
    h = f2bf(v); l = f2bf(v - bf2f(h));
    VWThi[j * 512 + b] = h; VWTlo[j * 512 + b] = l;
    float e = emb[b * 512 + j];
    short eh = f2bf(e);
    E[b * 512 + j] = eh;       // [k][d]
    ET[j * 512 + b] = eh;      // [d][k]
    esum += e * e;
  }
  for (int o = 32; o >= 1; o >>= 1) esum += __shfl_xor(esum, o);
  __shared__ float red[4];
  if ((tid & 63) == 0) red[tid >> 6] = esum;
  __syncthreads();
  if (tid == 0) enorm[b] = red[0] + red[1] + red[2] + red[3];
}

// ---------------- G1: x = inputs @ mean_W + mean_b (unchanged) ----------------
__global__ __launch_bounds__(256, 2) void k_gemm_mean(
    const float* __restrict__ inp, const short* __restrict__ Bhi, const short* __restrict__ Blo,
    const float* __restrict__ bias, short* __restrict__ Xhi, short* __restrict__ Xlo,
    float* __restrict__ xnorm)
{
  __shared__ short Ah[BM * BK], Al[BM * BK], Bh[BN * BK], Bl[BN * BK];
  int tid = threadIdx.x;
  int n0 = blockIdx.x * BM, c0 = blockIdx.y * BN;
  int lane = tid & 63, wid = tid >> 6;
  int wm = wid >> 1, wn = wid & 1;
  int q = lane >> 4, m = lane & 15;
  f32x4 acc[4][4];
#pragma unroll
  for (int i = 0; i < 4; i++)
#pragma unroll
    for (int j = 0; j < 4; j++)
#pragma unroll
      for (int r = 0; r < 4; r++) acc[i][j][r] = 0.f;

  for (int k0 = 0; k0 < DIMD; k0 += BK){
    __syncthreads();
    stage_f32_split(inp, n0, DIMD, k0, Ah, Al);
    stage_bf16(Bhi, c0, DIMD, k0, Bh);
    stage_bf16(Blo, c0, DIMD, k0, Bl);
    __syncthreads();
    bf16x8 ah[4], al[4], bh[4], bl[4];
#pragma unroll
    for (int i = 0; i < 4; i++){
      ah[i] = frag(Ah, wm * 64 + i * 16 + m, q);
      al[i] = frag(Al, wm * 64 + i * 16 + m, q);
      bh[i] = frag(Bh, wn * 64 + i * 16 + m, q);
      bl[i] = frag(Bl, wn * 64 + i * 16 + m, q);
    }
#pragma unroll
    for (int i = 0; i < 4; i++)
#pragma unroll
      for (int j = 0; j < 4; j++){
        acc[i][j] = __builtin_amdgcn_mfma_f32_16x16x32_bf16(ah[i], bh[j], acc[i][j], 0, 0, 0);
        acc[i][j] = __builtin_amdgcn_mfma_f32_16x16x32_bf16(ah[i], bl[j], acc[i][j], 0, 0, 0);
        acc[i][j] = __builtin_amdgcn_mfma_f32_16x16x32_bf16(al[i], bh[j], acc[i][j], 0, 0, 0);
      }
  }
#pragma unroll
  for (int i = 0; i < 4; i++){
#pragma unroll
    for (int r = 0; r < 4; r++){
      int row = n0 + wm * 64 + i * 16 + q * 4 + r;
      float xn = 0.f;
#pragma unroll
      for (int j = 0; j < 4; j++){
        int col = c0 + wn * 64 + j * 16 + m;
        float x = acc[i][j][r] + bias[col];
        short h = f2bf(x);
        short l = f2bf(x - bf2f(h));
        Xhi[(long)row * DIMD + col] = h;
        Xlo[(long)row * DIMD + col] = l;
        xn += x * x;
      }
      xn += __shfl_xor(xn, 1); xn += __shfl_xor(xn, 2);
      xn += __shfl_xor(xn, 4); xn += __shfl_xor(xn, 8);
      if (m == 0) atomicAdd(&xnorm[row], xn);
    }
  }
}

// ---------------- fused: zlv + S + softmax + quant + loss ----------------
// 1024 blocks x 512 threads; block owns 64 rows x all 512 codes.
// wave wid owns all 64 rows x 64 cols (cols wid*64..+64).
__global__ __launch_bounds__(512, 2) void k_fused(
    const short* __restrict__ Xh, const short* __restrict__ Xl,
    const short* __restrict__ Vh, const short* __restrict__ Vl,
    const short* __restrict__ Eb, const short* __restrict__ Et,
    const float* __restrict__ lvb, const float* __restrict__ xnorm,
    const float* __restrict__ enorm, const float* __restrict__ inp,
    float* __restrict__ probs, float* __restrict__ qout,
    float* __restrict__ Pacc, float* __restrict__ lossacc)
{
  __shared__ __align__(128) char pool[110592];
  short* Ah  = (short*)pool;                    // 4 KB  [64][32]
  short* Al  = (short*)(pool + 4096);           // 4 KB
  short* Bv0 = (short*)(pool + 8192);           // 32 KB [512][32] VW hi
  short* Bv1 = (short*)(pool + 40960);          // 32 KB VW lo
  short* Be  = (short*)(pool + 73728);          // 32 KB E / ET stage
  float* rrA = (float*)(pool + 106496);         // 2 KB  [64][8]
  float* rrB = (float*)(pool + 108544);         // 2 KB
  short* P   = (short*)(pool + 8192);           // 64 KB probs bf16 [64][512] (overlays Bv0/Bv1)

  const int tid = threadIdx.x;
  const int n0 = blockIdx.x * 64;
  const int lane = tid & 63, wid = tid >> 6;
  const int q = lane >> 4, m = lane & 15;
  const int c0 = wid * 64;

  f32x4 accZ[4][4];
  f32x4 accS[4][4];
#pragma unroll
  for (int i = 0; i < 4; i++)
#pragma unroll
    for (int j = 0; j < 4; j++)
#pragma unroll
      for (int r = 0; r < 4; r++) accZ[i][j][r] = 0.f;

  // ---- phase Z: zlv = x @ logvar_W (split bf16, 3 terms) ----
  stage_A64(Xh, Xl, n0, 0, Ah, Al);
  stage_B512(Vh, 0, Bv0);
  stage_B512(Vl, 0, Bv1);
  for (int k0 = 0; k0 < 512; k0 += 32){
    __syncthreads();                       // staged data for k0 ready (vmcnt drained here)
    bf16x8 ah[4], al[4], bh[4], bl[4];
#pragma unroll
    for (int i = 0; i < 4; i++){
      ah[i] = frag_s(Ah, i * 16 + m, q);
      al[i] = frag_s(Al, i * 16 + m, q);
    }
#pragma unroll
    for (int j = 0; j < 4; j++){
      bh[j] = frag_s(Bv0, c0 + j * 16 + m, q);
      bl[j] = frag_s(Bv1, c0 + j * 16 + m, q);
    }
    __syncthreads();                       // all waves hold frags; buffer free
    if (k0 < 480){                         // issue next stage; MFMAs below overlap its latency
      stage_A64(Xh, Xl, n0, k0 + 32, Ah, Al);
      stage_B512(Vh, k0 + 32, Bv0);
      stage_B512(Vl, k0 + 32, Bv1);
    }
#pragma unroll
    for (int j = 0; j < 4; j++)
#pragma unroll
      for (int i = 0; i < 4; i++){
        accZ[i][j] = __builtin_amdgcn_mfma_f32_16x16x32_bf16(ah[i], bh[j], accZ[i][j], 0, 0, 0);
        accZ[i][j] = __builtin_amdgcn_mfma_f32_16x16x32_bf16(ah[i], bl[j], accZ[i][j], 0, 0, 0);
        accZ[i][j] = __builtin_amdgcn_mfma_f32_16x16x32_bf16(al[i], bh[j], accZ[i][j], 0, 0, 0);
      }
  }

  // ---- phase S: S = x_hi @ E^T (plain bf16) ----
#pragma unroll
  for (int i = 0; i < 4; i++)
#pragma unroll
    for (int j = 0; j < 4; j++)
#pragma unroll
      for (int r = 0; r < 4; r++) accS[i][j][r] = 0.f;
  stage_A64h(Xh, n0, 0, Ah);
  stage_B512(Eb, 0, Be);
  for (int k0 = 0; k0 < 512; k0 += 32){
    __syncthreads();
    bf16x8 ah[4], be[4];
#pragma unroll
    for (int i = 0; i < 4; i++) ah[i] = frag_s(Ah, i * 16 + m, q);
#pragma unroll
    for (int j = 0; j < 4; j++) be[j] = frag_s(Be, c0 + j * 16 + m, q);
    __syncthreads();
    if (k0 < 480){
      stage_A64h(Xh, n0, k0 + 32, Ah);
      stage_B512(Eb, k0 + 32, Be);
    }
#pragma unroll
    for (int j = 0; j < 4; j++)
#pragma unroll
      for (int i = 0; i < 4; i++)
        accS[i][j] = __builtin_amdgcn_mfma_f32_16x16x32_bf16(ah[i], be[j], accS[i][j], 0, 0, 0);
  }

  // ---- logits (in-register) ----
  float lvbv[4], env[4];
#pragma unroll
  for (int j = 0; j < 4; j++){
    int col = c0 + j * 16 + m;
    lvbv[j] = lvb[col];
    env[j] = enorm[col];
  }
  float xnv[4][4];
#pragma unroll
  for (int i = 0; i < 4; i++)
#pragma unroll
    for (int r = 0; r < 4; r++) xnv[i][r] = xnorm[n0 + i * 16 + q * 4 + r];

  const float inv800 = 0.5f / 400.0f;
#pragma unroll
  for (int i = 0; i < 4; i++)
#pragma unroll
    for (int j = 0; j < 4; j++)
#pragma unroll
      for (int r = 0; r < 4; r++){
        float z = accZ[i][j][r] + lvbv[j];
        float s = accS[i][j][r];
        float sm = __expf(-2.f * z);
        accS[i][j][r] = z - inv800 * (xnv[i][r] + env[j] - 2.f * s) * sm;
      }

  // ---- softmax: row max ----
  float mxp[4][4];
#pragma unroll
  for (int i = 0; i < 4; i++)
#pragma unroll
    for (int r = 0; r < 4; r++){
      float v = accS[i][0][r];
#pragma unroll
      for (int j = 1; j < 4; j++) v = fmaxf(v, accS[i][j][r]);
      v = fmaxf(v, __shfl_xor(v, 1));
      v = fmaxf(v, __shfl_xor(v, 2));
      v = fmaxf(v, __shfl_xor(v, 4));
      v = fmaxf(v, __shfl_xor(v, 8));
      mxp[i][r] = v;
    }
  if (m == 0){
#pragma unroll
    for (int i = 0; i < 4; i++)
#pragma unroll
      for (int r = 0; r < 4; r++)
        rrA[(i * 16 + q * 4 + r) * 8 + wid] = mxp[i][r];
  }
  __syncthreads();
  float mxf[4][4];
#pragma unroll
  for (int i = 0; i < 4; i++)
#pragma unroll
    for (int r = 0; r < 4; r++){
      int row = i * 16 + q * 4 + r;
      float v = rrA[row * 8 + 0];
#pragma unroll
      for (int w = 1; w < 8; w++) v = fmaxf(v, rrA[row * 8 + w]);
      mxf[i][r] = v;
    }

  // ---- softmax: exp + row sum ----
  float smr[4][4];
#pragma unroll
  for (int i = 0; i < 4; i++)
#pragma unroll
    for (int r = 0; r < 4; r++){
      float sacc = 0.f;
#pragma unroll
      for (int j = 0; j < 4; j++){
        float p = __expf(accS[i][j][r] - mxf[i][r]);
        accS[i][j][r] = p;
        sacc += p;
      }
      sacc += __shfl_xor(sacc, 1);
      sacc += __shfl_xor(sacc, 2);
      sacc += __shfl_xor(sacc, 4);
      sacc += __shfl_xor(sacc, 8);
      smr[i][r] = sacc;
    }
  if (m == 0){
#pragma unroll
    for (int i = 0; i < 4; i++)
#pragma unroll
      for (int r = 0; r < 4; r++)
        rrB[(i * 16 + q * 4 + r) * 8 + wid] = smr[i][r];
  }
  __syncthreads();
#pragma unroll
  for (int i = 0; i < 4; i++)
#pragma unroll
    for (int r = 0; r < 4; r++){
      int row = i * 16 + q * 4 + r;
      float v = 0.f;
#pragma unroll
      for (int w = 0; w < 8; w++) v += rrB[row * 8 + w];
      smr[i][r] = v;
    }

  // ---- probs out (fp32 global), probs bf16 -> swizzled LDS, Pacc ----
  float pj[4];
#pragma unroll
  for (int j = 0; j < 4; j++) pj[j] = 0.f;
#pragma unroll
  for (int i = 0; i < 4; i++)
#pragma unroll
    for (int r = 0; r < 4; r++){
      int rowl = i * 16 + q * 4 + r;
      long rowg = n0 + rowl;
      float inv = 1.0f / smr[i][r];
#pragma unroll
      for (int j = 0; j < 4; j++){
        int col = c0 + j * 16 + m;
        float qv = accS[i][j][r] * inv;
        probs[rowg * 512 + col] = qv;
        pj[j] += qv;
        int cg = col >> 3;
        P[rowl * 512 + ((((cg ^ (rowl & 7)) << 3)) | (col & 7))] = f2bf(qv);
      }
    }
#pragma unroll
  for (int j = 0; j < 4; j++){
    pj[j] += __shfl_xor(pj[j], 16);
    pj[j] += __shfl_xor(pj[j], 32);
  }
  if (lane < 16){
#pragma unroll
    for (int j = 0; j < 4; j++) atomicAdd(&Pacc[c0 + j * 16 + m], pj[j]);
  }

  // ---- quant: q = probs_bf16 @ embedding (A from LDS, reuse accZ) ----
#pragma unroll
  for (int i = 0; i < 4; i++)
#pragma unroll
    for (int j = 0; j < 4; j++)
#pragma unroll
      for (int r = 0; r < 4; r++) accZ[i][j][r] = 0.f;
  stage_B512(Et, 0, Be);
  for (int k0 = 0; k0 < 512; k0 += 32){
    __syncthreads();                       // first iter: also fences all P ds_writes
    bf16x8 pa[4], bq[4];
#pragma unroll
    for (int i = 0; i < 4; i++){
      int rowl = i * 16 + m;
      int cg = (k0 >> 3) + q;
      pa[i] = *(const bf16x8*)(P + rowl * 512 + ((cg ^ (rowl & 7)) << 3));
    }
#pragma unroll
    for (int j = 0; j < 4; j++) bq[j] = frag_s(Be, c0 + j * 16 + m, q);
    __syncthreads();
    if (k0 < 480) stage_B512(Et, k0 + 32, Be);
#pragma unroll
    for (int j = 0; j < 4; j++)
#pragma unroll
      for (int i = 0; i < 4; i++)
        accZ[i][j] = __builtin_amdgcn_mfma_f32_16x16x32_bf16(pa[i], bq[j], accZ[i][j], 0, 0, 0);
  }

  // ---- quant epilogue: write qout, accumulate loss ----
  float lsum = 0.f;
#pragma unroll
  for (int i = 0; i < 4; i++)
#pragma unroll
    for (int r = 0; r < 4; r++){
      long rowg = n0 + i * 16 + q * 4 + r;
#pragma unroll
      for (int j = 0; j < 4; j++){
        int col = c0 + j * 16 + m;
        float qv = accZ[i][j][r];
        long idx = rowg * 512 + col;
        qout[idx] = qv;
        float d = qv - inp[idx];
        lsum += d * d;
      }
    }
  lsum += __shfl_xor(lsum, 32);
  lsum += __shfl_xor(lsum, 16);
  lsum += __shfl_xor(lsum, 8);
  lsum += __shfl_xor(lsum, 4);
  lsum += __shfl_xor(lsum, 2);
  lsum += __shfl_xor(lsum, 1);
  if (lane == 0) rrA[wid] = lsum;
  __syncthreads();
  if (tid == 0){
    float t = 0.f;
#pragma unroll
    for (int w = 0; w < 8; w++) t += rrA[w];
    atomicAdd(lossacc, t);
  }
}

// ---------------- G5: loss + perplexity ----------------
__global__ __launch_bounds__(256) void k_final(
    const float* __restrict__ Pacc, const float* __restrict__ lossacc, float* __restrict__ out)
{
  int tid = threadIdx.x;
  float h = 0.f;
  for (int k = tid; k < 512; k += 256){
    float a = Pacc[k] * (1.0f / 65536.0f);
    h += a * __logf(a + 1e-10f);
  }
  for (int o = 32; o >= 1; o >>= 1) h += __shfl_xor(h, o);
  __shared__ float red[4];
  if ((tid & 63) == 0) red[tid >> 6] = h;
  __syncthreads();
  if (tid == 0){
    float H = red[0] + red[1] + red[2] + red[3];
    out[0] = 1.25f * lossacc[0] * (1.0f / (float)NELEM);
    out[PERPOFF] = __expf(-H);
  }
}

extern "C" void kernel_launch(void* const* d_in, const int* in_sizes, int n_in,
                              void* d_out, int out_size, void* d_ws, size_t ws_size,
                              hipStream_t stream)
{
  const float* inp   = (const float*)d_in[0];
  const float* meanW = (const float*)d_in[1];
  const float* meanb = (const float*)d_in[2];
  const float* lvW   = (const float*)d_in[3];
  const float* lvb   = (const float*)d_in[4];
  const float* emb   = (const float*)d_in[5];
  float* out = (float*)d_out;

  // workspace carve
  char* w = (char*)d_ws;
  short* Xhi = (short*)w;   w += (size_t)NROWS * DIMD * 2;      // 67.1 MB
  short* Xlo = (short*)w;   w += (size_t)NROWS * DIMD * 2;      // 67.1 MB
  short* MWThi = (short*)w; w += 512 * 512 * 2;
  short* MWTlo = (short*)w; w += 512 * 512 * 2;
  short* VWThi = (short*)w; w += 512 * 512 * 2;
  short* VWTlo = (short*)w; w += 512 * 512 * 2;
  short* E     = (short*)w; w += 512 * 512 * 2;
  short* ET    = (short*)w; w += 512 * 512 * 2;
  float* enorm = (float*)w; w += 512 * 4;
  float* stats = (float*)w;                    // xnorm[65536] + Pacc[512] + lossacc
  float* xnorm   = stats;
  float* Pacc    = stats + NROWS;
  float* lossacc = stats + NROWS + 512;

  hipMemsetAsync(stats, 0, (size_t)(NROWS + 512 + 16) * 4, stream);

  k_convert_w<<<512, 256, 0, stream>>>(meanW, lvW, emb, MWThi, MWTlo, VWThi, VWTlo, E, ET, enorm);
  k_gemm_mean<<<dim3(512, 4), 256, 0, stream>>>(inp, MWThi, MWTlo, meanb, Xhi, Xlo, xnorm);
  k_fused<<<1024, 512, 0, stream>>>(Xhi, Xlo, VWThi, VWTlo, E, ET, lvb, xnorm, enorm, inp,
                                    out + PROBSOFF, out + QOFF, Pacc, lossacc);
  k_final<<<1, 256, 0, stream>>>(Pacc, lossacc, out);
}